// Round 1
// baseline (125.445 us; speedup 1.0000x reference)
//
#include <hip/hip_runtime.h>
#include <hip/hip_bf16.h>

#define NNODES 4096
#define CAP 256

// ---------------------------------------------------------------------------
// Edge extraction: mask row -> column list (deterministic order via prefix scan)
// ---------------------------------------------------------------------------
__global__ __launch_bounds__(256) void edge_build_kernel(
    const float* __restrict__ mask, int* __restrict__ deg, int* __restrict__ cols) {
  const int n = blockIdx.x;
  const int tid = threadIdx.x;
  const int lane = tid & 63, wid = tid >> 6;
  const float4* row = (const float4*)(mask + (size_t)n * NNODES);
  float4 v[4];
  int cnt = 0;
#pragma unroll
  for (int j = 0; j < 4; ++j) {
    v[j] = row[tid + 256 * j];  // coalesced: consecutive threads -> consecutive float4
    cnt += (v[j].x == 0.0f) + (v[j].y == 0.0f) + (v[j].z == 0.0f) + (v[j].w == 0.0f);
  }
  // exclusive prefix sum over 256 threads (wave scan + cross-wave)
  int x = cnt;
#pragma unroll
  for (int o = 1; o < 64; o <<= 1) {
    int y = __shfl_up(x, o);
    if (lane >= o) x += y;
  }
  __shared__ int wsum[4];
  if (lane == 63) wsum[wid] = x;
  __syncthreads();
  int base = 0;
  for (int w = 0; w < wid; ++w) base += wsum[w];
  int off = base + x - cnt;  // exclusive offset for this thread
  if (tid == 0) {
    int total = wsum[0] + wsum[1] + wsum[2] + wsum[3];
    deg[n] = total < CAP ? total : CAP;
  }
  int* dst = cols + (size_t)n * CAP;
#pragma unroll
  for (int j = 0; j < 4; ++j) {
    const int c0 = (tid + 256 * j) * 4;
    float fv[4] = {v[j].x, v[j].y, v[j].z, v[j].w};
#pragma unroll
    for (int k = 0; k < 4; ++k) {
      if (fv[k] == 0.0f) {
        if (off < CAP) dst[off] = c0 + k;
        ++off;
      }
    }
  }
}

// ---------------------------------------------------------------------------
// fp32 tiled GEMM + bias: C(MxN) = A(MxK) @ W(KxN) + b  (all dims % tile == 0)
// ---------------------------------------------------------------------------
template <int BK>
__global__ __launch_bounds__(256) void gemm_bias_kernel(
    const float* __restrict__ A, const float* __restrict__ W,
    const float* __restrict__ bias, float* __restrict__ C,
    int M, int K, int N) {
  __shared__ float As[64][BK + 1];
  __shared__ float Ws[BK][64 + 1];
  const int tid = threadIdx.x;
  const int tx = tid & 15, ty = tid >> 4;
  const int brow = blockIdx.y * 64, bcol = blockIdx.x * 64;
  float acc[4][4] = {};
  for (int k0 = 0; k0 < K; k0 += BK) {
    for (int i = tid; i < 64 * (BK / 4); i += 256) {
      int m = i / (BK / 4), k4 = i % (BK / 4);
      float4 v = *(const float4*)&A[(size_t)(brow + m) * K + k0 + k4 * 4];
      As[m][k4 * 4 + 0] = v.x; As[m][k4 * 4 + 1] = v.y;
      As[m][k4 * 4 + 2] = v.z; As[m][k4 * 4 + 3] = v.w;
    }
    for (int i = tid; i < BK * 16; i += 256) {
      int k = i / 16, c4 = i % 16;
      float4 v = *(const float4*)&W[(size_t)(k0 + k) * N + bcol + c4 * 4];
      Ws[k][c4 * 4 + 0] = v.x; Ws[k][c4 * 4 + 1] = v.y;
      Ws[k][c4 * 4 + 2] = v.z; Ws[k][c4 * 4 + 3] = v.w;
    }
    __syncthreads();
#pragma unroll
    for (int kk = 0; kk < BK; ++kk) {
      float a[4], w[4];
#pragma unroll
      for (int i = 0; i < 4; ++i) a[i] = As[ty * 4 + i][kk];
#pragma unroll
      for (int j = 0; j < 4; ++j) w[j] = Ws[kk][tx * 4 + j];
#pragma unroll
      for (int i = 0; i < 4; ++i)
#pragma unroll
        for (int j = 0; j < 4; ++j) acc[i][j] = fmaf(a[i], w[j], acc[i][j]);
    }
    __syncthreads();
  }
#pragma unroll
  for (int i = 0; i < 4; ++i) {
    int r = brow + ty * 4 + i;
#pragma unroll
    for (int j = 0; j < 4; ++j) {
      int c = bcol + tx * 4 + j;
      C[(size_t)r * N + c] = acc[i][j] + bias[c];
    }
  }
}

// ---------------------------------------------------------------------------
// s_src[n,h] = sum_f proj[n,h,f]*a_src[h,f]; s_tgt likewise. One wave per (n,h).
// ---------------------------------------------------------------------------
__global__ __launch_bounds__(256) void scores_kernel(
    const float* __restrict__ proj, const float* __restrict__ a_src,
    const float* __restrict__ a_tgt, float* __restrict__ s_src,
    float* __restrict__ s_tgt, int H) {
  const int g = blockIdx.x * 4 + (threadIdx.x >> 6);  // global wave id = n*H+h
  const int lane = threadIdx.x & 63;
  const int n = g / H, h = g - n * H;
  if (n >= NNODES) return;
  float p = proj[(size_t)n * (H * 64) + h * 64 + lane];
  float vs = p * a_src[h * 64 + lane];
  float vt = p * a_tgt[h * 64 + lane];
#pragma unroll
  for (int o = 32; o; o >>= 1) {
    vs += __shfl_down(vs, o);
    vt += __shfl_down(vt, o);
  }
  if (lane == 0) {
    s_src[(size_t)n * H + h] = vs;
    s_tgt[(size_t)n * H + h] = vt;
  }
}

// ---------------------------------------------------------------------------
// Sparse attention row: softmax over edges (exactly == masked dense softmax in
// fp32 since exp(-1e9) underflows to 0), then out[n,:] = sum_e w_e * proj[m_e,:]
// ---------------------------------------------------------------------------
template <int H>
__global__ void attn_kernel(
    const float* __restrict__ proj, const float* __restrict__ s_src,
    const float* __restrict__ s_tgt, const int* __restrict__ deg,
    const int* __restrict__ cols, float* __restrict__ out) {
  constexpr int F = 64;
  const int n = blockIdx.x;
  const int tid = threadIdx.x;
  const int nt = blockDim.x;
  __shared__ int sm_[CAP];
  __shared__ float sw[CAP * H];
  __shared__ float sinv[H];
  const int d = deg[n];
  for (int i = tid; i < d; i += nt) sm_[i] = cols[(size_t)n * CAP + i];
  __syncthreads();
  // raw leaky-relu scores
  for (int i = tid; i < d * H; i += nt) {
    int e = i / H, h = i % H;
    float s = s_src[n * H + h] + s_tgt[sm_[e] * H + h];
    sw[i] = s >= 0.f ? s : 0.2f * s;
  }
  __syncthreads();
  // per-head max + sum-exp (one wave per head, strided)
  const int lane = tid & 63, wid = tid >> 6, nw = (nt >> 6) ? (nt >> 6) : 1;
  for (int h = wid; h < H; h += nw) {
    float mx = -1e30f;
    for (int e = lane; e < d; e += 64) mx = fmaxf(mx, sw[e * H + h]);
#pragma unroll
    for (int o = 32; o; o >>= 1) mx = fmaxf(mx, __shfl_xor(mx, o));
    float sum = 0.f;
    for (int e = lane; e < d; e += 64) {
      float w = __expf(sw[e * H + h] - mx);
      sw[e * H + h] = w;
      sum += w;
    }
#pragma unroll
    for (int o = 32; o; o >>= 1) sum += __shfl_xor(sum, o);
    if (lane == 0) sinv[h] = 1.0f / sum;
  }
  __syncthreads();
  // gather-accumulate
  for (int o = tid; o < H * F; o += nt) {
    const int h = o >> 6;
    float acc = 0.f;
    for (int e = 0; e < d; ++e)
      acc = fmaf(sw[e * H + h], proj[(size_t)sm_[e] * (H * F) + o], acc);
    out[(size_t)n * (H * F) + o] = acc * sinv[h];
  }
}

// ---------------------------------------------------------------------------
extern "C" void kernel_launch(void* const* d_in, const int* in_sizes, int n_in,
                              void* d_out, int out_size, void* d_ws, size_t ws_size,
                              hipStream_t stream) {
  const float* x      = (const float*)d_in[0];
  const float* mask   = (const float*)d_in[1];
  const float* W0     = (const float*)d_in[2];
  const float* b0     = (const float*)d_in[3];
  const float* a_src0 = (const float*)d_in[4];
  const float* a_tgt0 = (const float*)d_in[5];
  const float* W1     = (const float*)d_in[6];
  const float* b1     = (const float*)d_in[7];
  const float* a_src1 = (const float*)d_in[8];
  const float* a_tgt1 = (const float*)d_in[9];
  float* out = (float*)d_out;

  // workspace layout (~22.3 MB)
  float* ws    = (float*)d_ws;
  float* proj0 = ws;                          // 4096*512
  float* h0    = proj0 + NNODES * 512;        // 4096*512
  float* proj1 = h0 + NNODES * 512;           // 4096*64
  float* ssrc0 = proj1 + NNODES * 64;         // 4096*8
  float* stgt0 = ssrc0 + NNODES * 8;          // 4096*8
  float* ssrc1 = stgt0 + NNODES * 8;          // 4096
  float* stgt1 = ssrc1 + NNODES;              // 4096
  int* deg  = (int*)(stgt1 + NNODES);         // 4096
  int* cols = deg + NNODES;                   // 4096*CAP

  // shared edge structure (same mask for both layers)
  edge_build_kernel<<<NNODES, 256, 0, stream>>>(mask, deg, cols);

  // ---- layer 0 (H=8, F=64) ----
  gemm_bias_kernel<32><<<dim3(512 / 64, NNODES / 64), 256, 0, stream>>>(
      x, W0, b0, proj0, NNODES, 128, 512);
  scores_kernel<<<(NNODES * 8) / 4, 256, 0, stream>>>(proj0, a_src0, a_tgt0,
                                                      ssrc0, stgt0, 8);
  attn_kernel<8><<<NNODES, 256, 0, stream>>>(proj0, ssrc0, stgt0, deg, cols, h0);

  // ---- layer 1 (H=1, F=64) ----
  gemm_bias_kernel<32><<<dim3(1, NNODES / 64), 256, 0, stream>>>(
      h0, W1, b1, proj1, NNODES, 512, 64);
  scores_kernel<<<NNODES / 4, 256, 0, stream>>>(proj1, a_src1, a_tgt1,
                                                ssrc1, stgt1, 1);
  attn_kernel<1><<<NNODES, 64, 0, stream>>>(proj1, ssrc1, stgt1, deg, cols, out);
}